// Round 6
// baseline (537.252 us; speedup 1.0000x reference)
//
#include <hip/hip_runtime.h>
#include <hip/hip_fp16.h>

#define D 1024
#define LOG2D 10
#define S_LEN 4096
#define BATCH 4
#define NROWS (BATCH * S_LEN) /* 16384 */
#define PI_F 3.14159265358979323846f

// padded LDS slot: one float2 pad per 16 -> breaks power-of-2 bank strides
#define SLOT(p) ((p) + ((p) >> 4))
#define FBUF 1088
#define NTW 341

typedef _Float16 f16x8 __attribute__((ext_vector_type(8)));
typedef float f32x4 __attribute__((ext_vector_type(4)));

__device__ __forceinline__ float2 cmul(float2 a, float2 b) {
    return make_float2(a.x * b.x - a.y * b.y, a.x * b.y + a.y * b.x);
}

__device__ __forceinline__ float fast_tanh(float v) {
    float e = __expf(2.0f * v);
    return 1.0f - 2.0f * __builtin_amdgcn_rcpf(e + 1.0f);
}

__device__ __forceinline__ void g2lds16(const void* g, void* l) {
    __builtin_amdgcn_global_load_lds(
        (const __attribute__((address_space(1))) unsigned int*)g,
        (__attribute__((address_space(3))) unsigned int*)l, 16, 0, 0);
}

// ---------------- fp32 -> fp16 conversion (x and the 4 weight matrices) ----
__global__ __launch_bounds__(256) void convert_all(
    const float* __restrict__ x,
    const float* __restrict__ w0, const float* __restrict__ w1,
    const float* __restrict__ w2, const float* __restrict__ w3,
    __half* __restrict__ xh,
    __half* __restrict__ h0, __half* __restrict__ h1,
    __half* __restrict__ h2, __half* __restrict__ h3)
{
    const int b = blockIdx.x;
    const float* s;
    __half* d;
    int li;
    if (b < 16384) { s = x; d = xh; li = b; }
    else {
        int t = b - 16384;
        int r = t >> 10;
        li = t & 1023;
        s = (r == 0) ? w0 : (r == 1) ? w1 : (r == 2) ? w2 : w3;
        d = (r == 0) ? h0 : (r == 1) ? h1 : (r == 2) ? h2 : h3;
    }
    const int idx = li * 256 + threadIdx.x;  // float4 index
    float4 v = ((const float4*)s)[idx];
    __half2 lo = __floats2half2_rn(v.x, v.y);
    __half2 hi = __floats2half2_rn(v.z, v.w);
    ((__half2*)d)[2 * idx + 0] = lo;
    ((__half2*)d)[2 * idx + 1] = hi;
}

// ------- Fused dual MFMA GEMM (round-4 proven structure, single-buffer) ----
__global__ __launch_bounds__(256, 2) void gemm_mfma2(
    const __half* __restrict__ Xh,
    const __half* __restrict__ W0, const float* __restrict__ b0, __half* __restrict__ O0,
    const __half* __restrict__ W1, const float* __restrict__ b1, __half* __restrict__ O1)
{
    const int idx = blockIdx.x;
    const int xcd = idx & 7;
    const int j = idx >> 3;           // 0..127
    const int n0 = (j & 7) * 128;
    const int m0 = (xcd * 16 + (j >> 3)) * 128;

    __shared__ __align__(16) __half As[128 * 32];
    __shared__ __align__(16) __half B0s[128 * 32];
    __shared__ __align__(16) __half B1s[128 * 32];

    const int tid = threadIdx.x;
    const int wave = tid >> 6;
    const int lane = tid & 63;

    const int srow = lane >> 2;                         // row in 16-row group
    const int schunk = (lane & 3) ^ ((lane >> 3) & 3);  // swizzled 16B chunk

    const __half* gA[2];
    const __half* gB0[2];
    const __half* gB1[2];
    __half* lA[2];
    __half* lB0[2];
    __half* lB1[2];
#pragma unroll
    for (int c = 0; c < 2; ++c) {
        const int rg = (wave * 2 + c) * 16 + srow;
        gA[c]  = Xh + (size_t)(m0 + rg) * 1024 + schunk * 8;
        gB0[c] = W0 + (size_t)(n0 + rg) * 1024 + schunk * 8;
        gB1[c] = W1 + (size_t)(n0 + rg) * 1024 + schunk * 8;
        lA[c]  = As  + (wave * 2 + c) * 512;
        lB0[c] = B0s + (wave * 2 + c) * 512;
        lB1[c] = B1s + (wave * 2 + c) * 512;
    }

    const int wm = (wave & 1) * 64;
    const int wn = (wave >> 1) * 64;
    const int quad = lane >> 4;
    const int l15 = lane & 15;

    int aoff[4], boff[4];
#pragma unroll
    for (int i = 0; i < 4; ++i) {
        const int Ra = wm + i * 16 + l15;
        aoff[i] = Ra * 32 + (quad ^ ((Ra >> 1) & 3)) * 8;
        const int Rb = wn + i * 16 + l15;
        boff[i] = Rb * 32 + (quad ^ ((Rb >> 1) & 3)) * 8;
    }

    f32x4 acc0[4][4], acc1[4][4];
#pragma unroll
    for (int i = 0; i < 4; ++i)
#pragma unroll
        for (int jj = 0; jj < 4; ++jj) {
            acc0[i][jj] = (f32x4){0.f, 0.f, 0.f, 0.f};
            acc1[i][jj] = (f32x4){0.f, 0.f, 0.f, 0.f};
        }

    for (int kt = 0; kt < 32; ++kt) {
        const int kh = kt * 32;
        __syncthreads();
        g2lds16(gA[0] + kh, lA[0]);
        g2lds16(gA[1] + kh, lA[1]);
        g2lds16(gB0[0] + kh, lB0[0]);
        g2lds16(gB0[1] + kh, lB0[1]);
        g2lds16(gB1[0] + kh, lB1[0]);
        g2lds16(gB1[1] + kh, lB1[1]);
        __syncthreads();

        f16x8 af[4], bf0[4], bf1[4];
#pragma unroll
        for (int i = 0; i < 4; ++i) af[i] = *(const f16x8*)(As + aoff[i]);
#pragma unroll
        for (int jj = 0; jj < 4; ++jj) {
            bf0[jj] = *(const f16x8*)(B0s + boff[jj]);
            bf1[jj] = *(const f16x8*)(B1s + boff[jj]);
        }
#pragma unroll
        for (int i = 0; i < 4; ++i)
#pragma unroll
            for (int jj = 0; jj < 4; ++jj) {
                acc0[i][jj] = __builtin_amdgcn_mfma_f32_16x16x32_f16(af[i], bf0[jj], acc0[i][jj], 0, 0, 0);
                acc1[i][jj] = __builtin_amdgcn_mfma_f32_16x16x32_f16(af[i], bf1[jj], acc1[i][jj], 0, 0, 0);
            }
    }

    // epilogue: C/D frag mapping col=lane&15, row=quad*4+reg
#pragma unroll
    for (int jj = 0; jj < 4; ++jj) {
        const int n = n0 + wn + jj * 16 + l15;
        const float bv0 = b0[n];
        const float bv1 = b1[n];
#pragma unroll
        for (int i = 0; i < 4; ++i) {
            const int mbase = m0 + wm + i * 16 + quad * 4;
#pragma unroll
            for (int r = 0; r < 4; ++r) {
                O0[(size_t)(mbase + r) * 1024 + n] = __float2half(fast_tanh(acc0[i][jj][r] + bv0));
                O1[(size_t)(mbase + r) * 1024 + n] = __float2half(fast_tanh(acc1[i][jj][r] + bv1));
            }
        }
    }
}

// -------- radix-4 Stockham FFT, length 1024, ONE WAVE (64 threads) --------
// Same algebra as the proven 256-thread version; each thread does 4
// butterflies per stage. __syncthreads() on a single-wave block has no
// cross-wave rendezvous cost.
__device__ __forceinline__ void build_twiddles_r4(float2* Wts, int tid) {
    for (int j = tid; j < NTW; j += 64) {
        int k, m;
        if (j == 0)      { k = 0;      m = 1;   }
        else if (j < 5)  { k = j - 1;  m = 4;   }
        else if (j < 21) { k = j - 5;  m = 16;  }
        else if (j < 85) { k = j - 21; m = 64;  }
        else             { k = j - 85; m = 256; }
        float ang = PI_F * (float)k / (2.0f * (float)m);
        Wts[j] = make_float2(cosf(ang), -sinf(ang));
    }
}

__device__ void fft1024_r4_w64(float2* bufA, float2* bufB, const float2* Wts,
                               float dir, int lane) {
    float2* src = bufA;
    float2* dst = bufB;
    int m = 1;
#pragma unroll
    for (int s = 0; s < 5; ++s) {
        __syncthreads();
#pragma unroll
        for (int u = 0; u < 4; ++u) {
            const int i = lane + (u << 6);  // 0..255
            const int k = i & (m - 1);
            const int jb = i >> (2 * s);
            float2 x0 = src[SLOT(i)];
            float2 x1 = src[SLOT(i + 256)];
            float2 x2 = src[SLOT(i + 512)];
            float2 x3 = src[SLOT(i + 768)];
            float2 y1, y2, y3;
            if (s == 0) { y1 = x1; y2 = x2; y3 = x3; }
            else {
                const int soff = (m - 1) / 3;
                float2 t1 = Wts[soff + k];
                t1.y *= dir;
                float2 t2 = cmul(t1, t1);
                float2 t3 = cmul(t1, t2);
                y1 = cmul(x1, t1);
                y2 = cmul(x2, t2);
                y3 = cmul(x3, t3);
            }
            float2 a = make_float2(x0.x + y2.x, x0.y + y2.y);
            float2 b = make_float2(x0.x - y2.x, x0.y - y2.y);
            float2 c = make_float2(y1.x + y3.x, y1.y + y3.y);
            float2 d = make_float2(y1.x - y3.x, y1.y - y3.y);
            float2 e = make_float2(dir * d.y, -dir * d.x);
            const int o = (jb << (2 * s + 2)) + k;
            dst[SLOT(o)]         = make_float2(a.x + c.x, a.y + c.y);
            dst[SLOT(o + m)]     = make_float2(b.x + e.x, b.y + e.y);
            dst[SLOT(o + 2 * m)] = make_float2(a.x - c.x, a.y - c.y);
            dst[SLOT(o + 3 * m)] = make_float2(b.x - e.x, b.y - e.y);
        }
        float2* t = src; src = dst; dst = t;
        m <<= 2;
    }
    __syncthreads();
}

// Per row: Z = FFT(k + i*v); Hermitian split; accumulate Fk*Fv into Fs[b].
#define ROWS_PER_BLOCK 8
__global__ __launch_bounds__(64) void bind_accum_kernel(
    const __half* __restrict__ K, const __half* __restrict__ V, float2* __restrict__ Fs)
{
    __shared__ __align__(16) float2 bufA[FBUF];
    __shared__ __align__(16) float2 bufB[FBUF];
    __shared__ __align__(16) float2 Wts[NTW];
    const int lane = threadIdx.x;
    build_twiddles_r4(Wts, lane);

    const int row0 = blockIdx.x * ROWS_PER_BLOCK;
    const int b = row0 >> 12;

    float2 accr[16];
#pragma unroll
    for (int h = 0; h < 16; ++h) accr[h] = make_float2(0.f, 0.f);

    for (int r = 0; r < ROWS_PER_BLOCK; ++r) {
        const size_t base = (size_t)(row0 + r) * D;
        const f16x8* Kv = (const f16x8*)(K + base);
        const f16x8* Vv = (const f16x8*)(V + base);
        // 16B/lane vector loads; lane owns elements [lane*16, lane*16+16)
        f16x8 k0 = Kv[lane * 2], k1 = Kv[lane * 2 + 1];
        f16x8 v0 = Vv[lane * 2], v1 = Vv[lane * 2 + 1];
        __syncthreads();  // prior iteration's bufA reads done
#pragma unroll
        for (int t = 0; t < 8; ++t) {
            bufA[SLOT(lane * 16 + t)]     = make_float2((float)k0[t], (float)v0[t]);
            bufA[SLOT(lane * 16 + 8 + t)] = make_float2((float)k1[t], (float)v1[t]);
        }
        fft1024_r4_w64(bufA, bufB, Wts, 1.0f, lane);  // Z in bufB
#pragma unroll
        for (int h = 0; h < 16; ++h) {
            const int j = lane + (h << 6);
            const int j2 = (D - j) & (D - 1);
            float2 Zt = bufB[SLOT(j)];
            float2 Zc = bufB[SLOT(j2)]; Zc.y = -Zc.y;
            float2 Fk = make_float2(0.5f * (Zt.x + Zc.x), 0.5f * (Zt.y + Zc.y));
            float2 Fv = make_float2(0.5f * (Zt.y - Zc.y), -0.5f * (Zt.x - Zc.x));
            float2 P = cmul(Fk, Fv);
            accr[h].x += P.x; accr[h].y += P.y;
        }
    }
#pragma unroll
    for (int h = 0; h < 16; ++h) {
        const int j = lane + (h << 6);
        atomicAdd(&Fs[(size_t)b * D + j].x, accr[h].x);
        atomicAdd(&Fs[(size_t)b * D + j].y, accr[h].y);
    }
}

// Per row: Z = FFT(q + i*r); g = conj(Fq) - |Fr|^2; y = ifft(Fs*g); out = x + Re(y)/D.
__global__ __launch_bounds__(64) void retrieve_kernel(
    const __half* __restrict__ Q, const __half* __restrict__ R,
    const float2* __restrict__ Fs, const float* __restrict__ x, float* __restrict__ out)
{
    __shared__ __align__(16) float2 bufA[FBUF];
    __shared__ __align__(16) float2 bufB[FBUF];
    __shared__ __align__(16) float2 Wts[NTW];
    const int lane = threadIdx.x;
    build_twiddles_r4(Wts, lane);

    const int row = blockIdx.x;
    const int b = row >> 12;
    const size_t base = (size_t)row * D;

    const f16x8* Qv = (const f16x8*)(Q + base);
    const f16x8* Rv = (const f16x8*)(R + base);
    f16x8 q0 = Qv[lane * 2], q1 = Qv[lane * 2 + 1];
    f16x8 r0 = Rv[lane * 2], r1 = Rv[lane * 2 + 1];
#pragma unroll
    for (int t = 0; t < 8; ++t) {
        bufA[SLOT(lane * 16 + t)]     = make_float2((float)q0[t], (float)r0[t]);
        bufA[SLOT(lane * 16 + 8 + t)] = make_float2((float)q1[t], (float)r1[t]);
    }
    fft1024_r4_w64(bufA, bufB, Wts, 1.0f, lane);  // Z in bufB

#pragma unroll
    for (int h = 0; h < 16; ++h) {
        const int j = lane + (h << 6);
        const int j2 = (D - j) & (D - 1);
        float2 Zt = bufB[SLOT(j)];
        float2 Zc = bufB[SLOT(j2)]; Zc.y = -Zc.y;
        float2 Fq = make_float2(0.5f * (Zt.x + Zc.x), 0.5f * (Zt.y + Zc.y));
        float2 Fr = make_float2(0.5f * (Zt.y - Zc.y), -0.5f * (Zt.x - Zc.x));
        float2 g  = make_float2(Fq.x - (Fr.x * Fr.x + Fr.y * Fr.y), -Fq.y);
        float2 Ff = Fs[(size_t)b * D + j];
        bufA[SLOT(j)] = cmul(Ff, g);
    }
    fft1024_r4_w64(bufA, bufB, Wts, -1.0f, lane);  // y in bufB (unscaled)

    const float inv = 1.0f / (float)D;
#pragma unroll
    for (int h = 0; h < 16; ++h) {
        const int j = lane + (h << 6);
        out[base + j] = x[base + j] + bufB[SLOT(j)].x * inv;
    }
}

extern "C" void kernel_launch(void* const* d_in, const int* in_sizes, int n_in,
                              void* d_out, int out_size, void* d_ws, size_t ws_size,
                              hipStream_t stream) {
    const float* x  = (const float*)d_in[0];
    const float* Wq = (const float*)d_in[1];
    const float* bq = (const float*)d_in[2];
    const float* Wk = (const float*)d_in[3];
    const float* bk = (const float*)d_in[4];
    const float* Wv = (const float*)d_in[5];
    const float* bv = (const float*)d_in[6];
    const float* Wr = (const float*)d_in[7];
    const float* br = (const float*)d_in[8];
    float* out = (float*)d_out;

    // ws: P0 (32MB fp16), P1 (32MB fp16), Fs (32KB)
    __half* P0 = (__half*)d_ws;
    __half* P1 = (__half*)((char*)d_ws + (size_t)NROWS * D * 2);
    float2* Fs = (float2*)((char*)d_ws + (size_t)NROWS * D * 4);

    // d_out doubles as fp16 scratch until the final kernel rewrites all of it
    __half* Xh  = (__half*)d_out;
    __half* Whk = (__half*)d_out + (size_t)16 * 1024 * 1024;
    __half* Whv = Whk + (size_t)1024 * 1024;
    __half* Whq = Whv + (size_t)1024 * 1024;
    __half* Whr = Whq + (size_t)1024 * 1024;

    convert_all<<<16384 + 4 * 1024, 256, 0, stream>>>(
        x, Wk, Wv, Wq, Wr, Xh, Whk, Whv, Whq, Whr);

    hipMemsetAsync(Fs, 0, (size_t)BATCH * D * sizeof(float2), stream);

    gemm_mfma2<<<1024, 256, 0, stream>>>(Xh, Whk, bk, P0, Whv, bv, P1);
    bind_accum_kernel<<<NROWS / ROWS_PER_BLOCK, 64, 0, stream>>>(P0, P1, Fs);
    gemm_mfma2<<<1024, 256, 0, stream>>>(Xh, Whq, bq, P0, Whr, br, P1);
    retrieve_kernel<<<NROWS, 64, 0, stream>>>(P0, P1, Fs, x, out);
}

// Round 7
// 467.675 us; speedup vs baseline: 1.1488x; 1.1488x over previous
//
#include <hip/hip_runtime.h>
#include <hip/hip_fp16.h>

#define D 1024
#define LOG2D 10
#define S_LEN 4096
#define BATCH 4
#define NROWS (BATCH * S_LEN) /* 16384 */
#define PI_F 3.14159265358979323846f

// padded LDS slot: one float2 pad per 16 -> breaks power-of-2 bank strides
#define SLOT(p) ((p) + ((p) >> 4))
#define FBUF 1088
#define NTW 341

typedef _Float16 f16x8 __attribute__((ext_vector_type(8)));
typedef float f32x4 __attribute__((ext_vector_type(4)));

__device__ __forceinline__ float2 cmul(float2 a, float2 b) {
    return make_float2(a.x * b.x - a.y * b.y, a.x * b.y + a.y * b.x);
}

__device__ __forceinline__ float fast_tanh(float v) {
    float e = __expf(2.0f * v);
    return 1.0f - 2.0f * __builtin_amdgcn_rcpf(e + 1.0f);
}

__device__ __forceinline__ void g2lds16(const void* g, void* l) {
    __builtin_amdgcn_global_load_lds(
        (const __attribute__((address_space(1))) unsigned int*)g,
        (__attribute__((address_space(3))) unsigned int*)l, 16, 0, 0);
}

// ---------------- fp32 -> fp16 conversion (x and the 4 weight matrices) ----
__global__ __launch_bounds__(256) void convert_all(
    const float* __restrict__ x,
    const float* __restrict__ w0, const float* __restrict__ w1,
    const float* __restrict__ w2, const float* __restrict__ w3,
    __half* __restrict__ xh,
    __half* __restrict__ h0, __half* __restrict__ h1,
    __half* __restrict__ h2, __half* __restrict__ h3)
{
    const int b = blockIdx.x;
    const float* s;
    __half* d;
    int li;
    if (b < 16384) { s = x; d = xh; li = b; }
    else {
        int t = b - 16384;
        int r = t >> 10;
        li = t & 1023;
        s = (r == 0) ? w0 : (r == 1) ? w1 : (r == 2) ? w2 : w3;
        d = (r == 0) ? h0 : (r == 1) ? h1 : (r == 2) ? h2 : h3;
    }
    const int idx = li * 256 + threadIdx.x;  // float4 index
    float4 v = ((const float4*)s)[idx];
    __half2 lo = __floats2half2_rn(v.x, v.y);
    __half2 hi = __floats2half2_rn(v.z, v.w);
    ((__half2*)d)[2 * idx + 0] = lo;
    ((__half2*)d)[2 * idx + 1] = hi;
}

// ------- Fused dual MFMA GEMM: O{0,1} = tanh(Xh * W{0,1}^T + b{0,1}) -------
// 128x128 tile, BK=64 (16 k-tiles, 64 MFMA per barrier pair), 256 thr.
// LDS [row][64] halves, 8 chunks of 16B per row, chunk q stored at slot
// q ^ (row&7) -> global_load_lds stays lane-contiguous, ds_read_b128 2-way max.
// XCD-swizzled block mapping for L2 locality.
__global__ __launch_bounds__(256, 2) void gemm_mfma2(
    const __half* __restrict__ Xh,
    const __half* __restrict__ W0, const float* __restrict__ b0, __half* __restrict__ O0,
    const __half* __restrict__ W1, const float* __restrict__ b1, __half* __restrict__ O1)
{
    const int idx = blockIdx.x;
    const int xcd = idx & 7;
    const int j = idx >> 3;           // 0..127
    const int n0 = (j & 7) * 128;
    const int m0 = (xcd * 16 + (j >> 3)) * 128;

    __shared__ __align__(16) __half As[128 * 64];
    __shared__ __align__(16) __half B0s[128 * 64];
    __shared__ __align__(16) __half B1s[128 * 64];

    const int tid = threadIdx.x;
    const int wave = tid >> 6;
    const int lane = tid & 63;

    // staging: one g2lds = 64 lanes x 16B = 8 rows x 8 chunks.
    // lane -> row (lane>>3), LDS chunk slot (lane&7); global chunk =
    // slot ^ (row&7) = (lane&7) ^ (lane>>3).
    const int srow = lane >> 3;
    const int schunk = (lane & 7) ^ (lane >> 3);

    const __half* gA[4];
    const __half* gB0[4];
    const __half* gB1[4];
    int loff[4];
#pragma unroll
    for (int c = 0; c < 4; ++c) {
        const int rbase = wave * 32 + c * 8;         // multiple of 8
        gA[c]  = Xh + (size_t)(m0 + rbase + srow) * 1024 + schunk * 8;
        gB0[c] = W0 + (size_t)(n0 + rbase + srow) * 1024 + schunk * 8;
        gB1[c] = W1 + (size_t)(n0 + rbase + srow) * 1024 + schunk * 8;
        loff[c] = rbase * 64;                         // half units
    }

    const int wm = (wave & 1) * 64;
    const int wn = (wave >> 1) * 64;
    const int quad = lane >> 4;
    const int l15 = lane & 15;

    // frag read offsets: row R, k-slice kk (0/1): chunk c=(kk<<2)|quad at
    // slot c ^ (R&7); R&7 = l15&7 here (wm, i*16 are multiples of 8).
    int aoff[2][4], boff[2][4];
#pragma unroll
    for (int kk = 0; kk < 2; ++kk)
#pragma unroll
        for (int i = 0; i < 4; ++i) {
            const int Ra = wm + i * 16 + l15;
            aoff[kk][i] = Ra * 64 + ((((kk << 2) | quad)) ^ (l15 & 7)) * 8;
            const int Rb = wn + i * 16 + l15;
            boff[kk][i] = Rb * 64 + ((((kk << 2) | quad)) ^ (l15 & 7)) * 8;
        }

    f32x4 acc0[4][4], acc1[4][4];
#pragma unroll
    for (int i = 0; i < 4; ++i)
#pragma unroll
        for (int jj = 0; jj < 4; ++jj) {
            acc0[i][jj] = (f32x4){0.f, 0.f, 0.f, 0.f};
            acc1[i][jj] = (f32x4){0.f, 0.f, 0.f, 0.f};
        }

    for (int kt = 0; kt < 16; ++kt) {
        const int kh = kt * 64;
        __syncthreads();
#pragma unroll
        for (int c = 0; c < 4; ++c) {
            g2lds16(gA[c] + kh,  As  + loff[c]);
            g2lds16(gB0[c] + kh, B0s + loff[c]);
            g2lds16(gB1[c] + kh, B1s + loff[c]);
        }
        __syncthreads();

#pragma unroll
        for (int kk = 0; kk < 2; ++kk) {
            f16x8 af[4], bf0[4], bf1[4];
#pragma unroll
            for (int i = 0; i < 4; ++i) af[i] = *(const f16x8*)(As + aoff[kk][i]);
#pragma unroll
            for (int jj = 0; jj < 4; ++jj) {
                bf0[jj] = *(const f16x8*)(B0s + boff[kk][jj]);
                bf1[jj] = *(const f16x8*)(B1s + boff[kk][jj]);
            }
#pragma unroll
            for (int i = 0; i < 4; ++i)
#pragma unroll
                for (int jj = 0; jj < 4; ++jj) {
                    acc0[i][jj] = __builtin_amdgcn_mfma_f32_16x16x32_f16(af[i], bf0[jj], acc0[i][jj], 0, 0, 0);
                    acc1[i][jj] = __builtin_amdgcn_mfma_f32_16x16x32_f16(af[i], bf1[jj], acc1[i][jj], 0, 0, 0);
                }
        }
    }

    // epilogue: C/D frag mapping col=lane&15, row=quad*4+reg
#pragma unroll
    for (int jj = 0; jj < 4; ++jj) {
        const int n = n0 + wn + jj * 16 + l15;
        const float bv0 = b0[n];
        const float bv1 = b1[n];
#pragma unroll
        for (int i = 0; i < 4; ++i) {
            const int mbase = m0 + wm + i * 16 + quad * 4;
#pragma unroll
            for (int r = 0; r < 4; ++r) {
                O0[(size_t)(mbase + r) * 1024 + n] = __float2half(fast_tanh(acc0[i][jj][r] + bv0));
                O1[(size_t)(mbase + r) * 1024 + n] = __float2half(fast_tanh(acc1[i][jj][r] + bv1));
            }
        }
    }
}

// ------ radix-4 Stockham FFT, length 1024, 256 threads (r4 proven) --------
__device__ __forceinline__ void build_twiddles_r4(float2* Wts, int tid) {
    for (int j = tid; j < NTW; j += 256) {
        int k, m;
        if (j == 0)      { k = 0;      m = 1;   }
        else if (j < 5)  { k = j - 1;  m = 4;   }
        else if (j < 21) { k = j - 5;  m = 16;  }
        else if (j < 85) { k = j - 21; m = 64;  }
        else             { k = j - 85; m = 256; }
        float ang = PI_F * (float)k / (2.0f * (float)m);
        Wts[j] = make_float2(cosf(ang), -sinf(ang));
    }
}

__device__ void fft1024_r4(float2* bufA, float2* bufB, const float2* Wts,
                           float dir, int tid) {
    float2* src = bufA;
    float2* dst = bufB;
    int m = 1;
#pragma unroll
    for (int s = 0; s < 5; ++s) {
        __syncthreads();
        const int k = tid & (m - 1);
        const int jb = tid >> (2 * s);
        float2 x0 = src[SLOT(tid)];
        float2 x1 = src[SLOT(tid + 256)];
        float2 x2 = src[SLOT(tid + 512)];
        float2 x3 = src[SLOT(tid + 768)];
        float2 y1, y2, y3;
        if (s == 0) { y1 = x1; y2 = x2; y3 = x3; }
        else {
            const int soff = (m - 1) / 3;
            float2 t1 = Wts[soff + k];
            t1.y *= dir;
            float2 t2 = cmul(t1, t1);
            float2 t3 = cmul(t1, t2);
            y1 = cmul(x1, t1);
            y2 = cmul(x2, t2);
            y3 = cmul(x3, t3);
        }
        float2 a = make_float2(x0.x + y2.x, x0.y + y2.y);
        float2 b = make_float2(x0.x - y2.x, x0.y - y2.y);
        float2 c = make_float2(y1.x + y3.x, y1.y + y3.y);
        float2 d = make_float2(y1.x - y3.x, y1.y - y3.y);
        float2 e = make_float2(dir * d.y, -dir * d.x);
        const int o = (jb << (2 * s + 2)) + k;
        dst[SLOT(o)]         = make_float2(a.x + c.x, a.y + c.y);
        dst[SLOT(o + m)]     = make_float2(b.x + e.x, b.y + e.y);
        dst[SLOT(o + 2 * m)] = make_float2(a.x - c.x, a.y - c.y);
        dst[SLOT(o + 3 * m)] = make_float2(b.x - e.x, b.y - e.y);
        float2* t = src; src = dst; dst = t;
        m <<= 2;
    }
    __syncthreads();
}

#define ROWS_PER_BLOCK 8
__global__ __launch_bounds__(256) void bind_accum_kernel(
    const __half* __restrict__ K, const __half* __restrict__ V, float2* __restrict__ Fs)
{
    __shared__ __align__(16) float2 bufA[FBUF];
    __shared__ __align__(16) float2 bufB[FBUF];
    __shared__ __align__(16) float2 Wts[NTW];
    const int tid = threadIdx.x;
    build_twiddles_r4(Wts, tid);

    const int row0 = blockIdx.x * ROWS_PER_BLOCK;
    const int b = row0 >> 12;

    float2 accr[4];
#pragma unroll
    for (int h = 0; h < 4; ++h) accr[h] = make_float2(0.f, 0.f);

    for (int r = 0; r < ROWS_PER_BLOCK; ++r) {
        const size_t base = (size_t)(row0 + r) * D;
#pragma unroll
        for (int h = 0; h < 4; ++h) {
            const int j = tid + (h << 8);
            bufA[SLOT(j)] = make_float2(__half2float(K[base + j]), __half2float(V[base + j]));
        }
        fft1024_r4(bufA, bufB, Wts, 1.0f, tid);  // Z in bufB
#pragma unroll
        for (int h = 0; h < 4; ++h) {
            const int j = tid + (h << 8);
            const int j2 = (D - j) & (D - 1);
            float2 Zt = bufB[SLOT(j)];
            float2 Zc = bufB[SLOT(j2)]; Zc.y = -Zc.y;
            float2 Fk = make_float2(0.5f * (Zt.x + Zc.x), 0.5f * (Zt.y + Zc.y));
            float2 Fv = make_float2(0.5f * (Zt.y - Zc.y), -0.5f * (Zt.x - Zc.x));
            float2 P = cmul(Fk, Fv);
            accr[h].x += P.x; accr[h].y += P.y;
        }
    }
#pragma unroll
    for (int h = 0; h < 4; ++h) {
        const int j = tid + (h << 8);
        atomicAdd(&Fs[(size_t)b * D + j].x, accr[h].x);
        atomicAdd(&Fs[(size_t)b * D + j].y, accr[h].y);
    }
}

__global__ __launch_bounds__(256) void retrieve_kernel(
    const __half* __restrict__ Q, const __half* __restrict__ R,
    const float2* __restrict__ Fs, const float* __restrict__ x, float* __restrict__ out)
{
    __shared__ __align__(16) float2 bufA[FBUF];
    __shared__ __align__(16) float2 bufB[FBUF];
    __shared__ __align__(16) float2 Wts[NTW];
    const int tid = threadIdx.x;
    build_twiddles_r4(Wts, tid);

    const int row = blockIdx.x;
    const int b = row >> 12;
    const size_t base = (size_t)row * D;

#pragma unroll
    for (int h = 0; h < 4; ++h) {
        const int j = tid + (h << 8);
        bufA[SLOT(j)] = make_float2(__half2float(Q[base + j]), __half2float(R[base + j]));
    }
    fft1024_r4(bufA, bufB, Wts, 1.0f, tid);  // Z in bufB

#pragma unroll
    for (int h = 0; h < 4; ++h) {
        const int j = tid + (h << 8);
        const int j2 = (D - j) & (D - 1);
        float2 Zt = bufB[SLOT(j)];
        float2 Zc = bufB[SLOT(j2)]; Zc.y = -Zc.y;
        float2 Fq = make_float2(0.5f * (Zt.x + Zc.x), 0.5f * (Zt.y + Zc.y));
        float2 Fr = make_float2(0.5f * (Zt.y - Zc.y), -0.5f * (Zt.x - Zc.x));
        float2 g  = make_float2(Fq.x - (Fr.x * Fr.x + Fr.y * Fr.y), -Fq.y);
        float2 Ff = Fs[(size_t)b * D + j];
        bufA[SLOT(j)] = cmul(Ff, g);
    }
    fft1024_r4(bufA, bufB, Wts, -1.0f, tid);  // y in bufB (unscaled)

    const float inv = 1.0f / (float)D;
#pragma unroll
    for (int h = 0; h < 4; ++h) {
        const int j = tid + (h << 8);
        out[base + j] = x[base + j] + bufB[SLOT(j)].x * inv;
    }
}

extern "C" void kernel_launch(void* const* d_in, const int* in_sizes, int n_in,
                              void* d_out, int out_size, void* d_ws, size_t ws_size,
                              hipStream_t stream) {
    const float* x  = (const float*)d_in[0];
    const float* Wq = (const float*)d_in[1];
    const float* bq = (const float*)d_in[2];
    const float* Wk = (const float*)d_in[3];
    const float* bk = (const float*)d_in[4];
    const float* Wv = (const float*)d_in[5];
    const float* bv = (const float*)d_in[6];
    const float* Wr = (const float*)d_in[7];
    const float* br = (const float*)d_in[8];
    float* out = (float*)d_out;

    // ws: P0 (32MB fp16), P1 (32MB fp16), Fs (32KB)
    __half* P0 = (__half*)d_ws;
    __half* P1 = (__half*)((char*)d_ws + (size_t)NROWS * D * 2);
    float2* Fs = (float2*)((char*)d_ws + (size_t)NROWS * D * 4);

    // d_out doubles as fp16 scratch until the final kernel rewrites all of it
    __half* Xh  = (__half*)d_out;
    __half* Whk = (__half*)d_out + (size_t)16 * 1024 * 1024;
    __half* Whv = Whk + (size_t)1024 * 1024;
    __half* Whq = Whv + (size_t)1024 * 1024;
    __half* Whr = Whq + (size_t)1024 * 1024;

    convert_all<<<16384 + 4 * 1024, 256, 0, stream>>>(
        x, Wk, Wv, Wq, Wr, Xh, Whk, Whv, Whq, Whr);

    hipMemsetAsync(Fs, 0, (size_t)BATCH * D * sizeof(float2), stream);

    gemm_mfma2<<<1024, 256, 0, stream>>>(Xh, Whk, bk, P0, Whv, bv, P1);
    bind_accum_kernel<<<NROWS / ROWS_PER_BLOCK, 256, 0, stream>>>(P0, P1, Fs);
    gemm_mfma2<<<1024, 256, 0, stream>>>(Xh, Whq, bq, P0, Whr, br, P1);
    retrieve_kernel<<<NROWS, 256, 0, stream>>>(P0, P1, Fs, x, out);
}